// Round 11
// baseline (308.524 us; speedup 1.0000x reference)
//
#include <hip/hip_runtime.h>
#include <hip/hip_bf16.h>
#include <hip/hip_cooperative_groups.h>
#include <math.h>

namespace cg = cooperative_groups;

// Problem constants
constexpr int B = 16;
constexpr int S = 2048;
constexpr int H = 1024;
constexpr int E = 2048;

// ---------------------------------------------------------------------------
// K1 (cooperative, grid=256x256): entire matvec chain in ONE node.
//  s1: qp[b,h]   = dot(query[b,:], W_q[h,:])          wave-per-row, 16 b-accums
//  s2: qwp[z]    = 16-row W_bil partials (64 chunks)   256 blocks
//  s3: qw        = sum_z qwp[z]                        64 blocks
//  s4: up[z]     = 32-row W_enc partials (32 chunks)   256 blocks
//  s5: u         = sum_z up[z]                         128 blocks
// Each weight matrix is read exactly once. No atomics -> deterministic.
// ---------------------------------------------------------------------------
__global__ __launch_bounds__(256)
void k_chain_coop(const float* __restrict__ query,
                  const float* __restrict__ W_q,
                  const float* __restrict__ W_bil,
                  const float* __restrict__ W_enc,
                  float* __restrict__ qp,
                  float* __restrict__ qwp,
                  float* __restrict__ qw,
                  float* __restrict__ up,
                  float* __restrict__ u) {
    cg::grid_group grid = cg::this_grid();
    __shared__ float qpl[B][16];   // 1 KB (stage 2)
    __shared__ float qwl[B][32];   // 2 KB (stage 4)
    int tid = threadIdx.x, bid = blockIdx.x;
    int wave = tid >> 6, lane = tid & 63;

    // ---- stage 1: qp. 1024 rows; block bid handles rows bid*4 + wave.
    {
        int h = bid * 4 + wave;
        const float4* wrow = (const float4*)(W_q + (size_t)h * H);
        float acc[B];
        #pragma unroll
        for (int b = 0; b < B; ++b) acc[b] = 0.f;
        #pragma unroll
        for (int i = 0; i < 4; ++i) {
            float4 w = wrow[i * 64 + lane];
            #pragma unroll
            for (int b = 0; b < B; ++b) {
                float4 q = ((const float4*)(query + b * H))[i * 64 + lane];
                acc[b] += w.x * q.x + w.y * q.y + w.z * q.z + w.w * q.w;
            }
        }
        #pragma unroll
        for (int off = 32; off; off >>= 1)
            #pragma unroll
            for (int b = 0; b < B; ++b)
                acc[b] += __shfl_down(acc[b], off, 64);
        if (lane == 0) {
            #pragma unroll
            for (int b = 0; b < B; ++b) qp[b * H + h] = acc[b];
        }
    }
    grid.sync();

    // ---- stage 2: qwp[z][b][col] = sum_{j<16} qp[b,z*16+j]*W_bil[z*16+j,col]
    // bid = cg*64 + z : cg in 0..3 (col group of 256), z in 0..63.
    {
        int cgi = bid >> 6, z = bid & 63;
        if (tid < B * 16) {
            int b = tid >> 4, j = tid & 15;
            qpl[b][j] = qp[b * H + z * 16 + j];
        }
        __syncthreads();
        int col = cgi * 256 + tid;
        float acc[B];
        #pragma unroll
        for (int b = 0; b < B; ++b) acc[b] = 0.f;
        #pragma unroll
        for (int j = 0; j < 16; ++j) {
            float w = W_bil[(size_t)(z * 16 + j) * H + col];
            #pragma unroll
            for (int b = 0; b < B; ++b) acc[b] += qpl[b][j] * w;
        }
        #pragma unroll
        for (int b = 0; b < B; ++b)
            qwp[((size_t)z * B + b) * H + col] = acc[b];
    }
    grid.sync();

    // ---- stage 3: qw = sum_z qwp[z]. B*H = 16384 -> blocks 0..63.
    if (bid < 64) {
        int idx = bid * 256 + tid;
        float a = 0.f;
        #pragma unroll
        for (int z = 0; z < 64; ++z) a += qwp[(size_t)z * (B * H) + idx];
        qw[idx] = a;
    }
    grid.sync();

    // ---- stage 4: up[z][b][col] = sum_{j<32} qw[b,z*32+j]*W_enc[z*32+j,col]
    // bid = eg*32 + z : eg in 0..7 (col group of 256), z in 0..31.
    {
        int eg = bid >> 5, z = bid & 31;
        for (int k = tid; k < B * 32; k += 256) {
            int b = k >> 5, j = k & 31;
            qwl[b][j] = qw[b * H + z * 32 + j];
        }
        __syncthreads();
        int col = eg * 256 + tid;
        float acc[B];
        #pragma unroll
        for (int b = 0; b < B; ++b) acc[b] = 0.f;
        #pragma unroll
        for (int j = 0; j < 32; ++j) {
            float w = W_enc[(size_t)(z * 32 + j) * E + col];
            #pragma unroll
            for (int b = 0; b < B; ++b) acc[b] += qwl[b][j] * w;
        }
        #pragma unroll
        for (int b = 0; b < B; ++b)
            up[((size_t)z * B + b) * E + col] = acc[b];
    }
    grid.sync();

    // ---- stage 5: u = sum_z up[z]. B*E = 32768 -> blocks 0..127.
    if (bid < 128) {
        int idx = bid * 256 + tid;
        float a = 0.f;
        #pragma unroll
        for (int z = 0; z < 32; ++z) a += up[(size_t)z * (B * E) + idx];
        u[idx] = a;
    }
}

// ---------------------------------------------------------------------------
// K2: scores[b,s] = mask ? dot(u[b,:], value[b,s,:]) : -inf   (proven)
// ---------------------------------------------------------------------------
__global__ void k_scores(const float* __restrict__ u,
                         const float* __restrict__ value,
                         const int* __restrict__ mask,
                         float* __restrict__ scores) {
    int b = blockIdx.y;
    int w = threadIdx.x >> 6;
    int lane = threadIdx.x & 63;
    const float4* u4 = (const float4*)(u + (size_t)b * E);
    float4 uu[8];
    #pragma unroll
    for (int i = 0; i < 8; ++i) uu[i] = u4[i * 64 + lane];
    int s0 = blockIdx.x * 16 + w * 4;
    #pragma unroll
    for (int r = 0; r < 4; r += 2) {
        int s = s0 + r;
        const float4* v0 = (const float4*)(value + ((size_t)(b * S + s)) * E);
        const float4* v1 = (const float4*)(value + ((size_t)(b * S + s + 1)) * E);
        float a0 = 0.f, a1 = 0.f;
        #pragma unroll
        for (int i = 0; i < 8; ++i) {
            float4 x0 = v0[i * 64 + lane];
            float4 x1 = v1[i * 64 + lane];
            a0 += x0.x * uu[i].x + x0.y * uu[i].y + x0.z * uu[i].z + x0.w * uu[i].w;
            a1 += x1.x * uu[i].x + x1.y * uu[i].y + x1.z * uu[i].z + x1.w * uu[i].w;
        }
        #pragma unroll
        for (int off = 32; off; off >>= 1) {
            a0 += __shfl_down(a0, off, 64);
            a1 += __shfl_down(a1, off, 64);
        }
        if (lane == 0) {
            scores[b * S + s]     = mask[b * S + s]     ? a0 : -INFINITY;
            scores[b * S + s + 1] = mask[b * S + s + 1] ? a1 : -INFINITY;
        }
    }
}

// ---------------------------------------------------------------------------
// K3: softmax + alphas + context, one block per batch.  (proven)
// Skip bound: alpha <= 1e-8 rows contribute <= 2048*1e-8*max|v| ~ 1e-4
// << 7.75e-2 threshold. Threshold test is block-uniform (LDS value).
// ---------------------------------------------------------------------------
__global__ void k_smctx(const float* __restrict__ scores,
                        const float* __restrict__ value,
                        float* __restrict__ alphas,
                        float* __restrict__ context) {
    __shared__ float sc[S];        // 8KB
    __shared__ float red[256];
    int b = blockIdx.x;
    int tid = threadIdx.x;
    const float* srow = scores + b * S;
    float m = -INFINITY;
    for (int s = tid; s < S; s += 256) {
        float v = srow[s];
        sc[s] = v;
        m = fmaxf(m, v);
    }
    red[tid] = m;
    __syncthreads();
    for (int off = 128; off; off >>= 1) {
        if (tid < off) red[tid] = fmaxf(red[tid], red[tid + off]);
        __syncthreads();
    }
    m = red[0];
    __syncthreads();
    float l = 0.f;
    for (int s = tid; s < S; s += 256) {
        float p = __expf(sc[s] - m);
        sc[s] = p;
        l += p;
    }
    red[tid] = l;
    __syncthreads();
    for (int off = 128; off; off >>= 1) {
        if (tid < off) red[tid] += red[tid + off];
        __syncthreads();
    }
    float lsum = red[0];
    float inv = 1.f / lsum;
    float thresh = 1e-8f * lsum;    // p > thresh  <=>  alpha > 1e-8
    for (int s = tid; s < S; s += 256)
        alphas[b * S + s] = sc[s] * inv;
    __syncthreads();
    float4 acc0 = {0.f, 0.f, 0.f, 0.f}, acc1 = {0.f, 0.f, 0.f, 0.f};
    for (int s = 0; s < S; ++s) {
        float p = sc[s];
        if (p > thresh) {           // block-uniform -> no divergence
            const float4* vrow = (const float4*)(value + (size_t)(b * S + s) * E);
            float4 v0 = vrow[tid];
            float4 v1 = vrow[256 + tid];
            acc0.x += p * v0.x; acc0.y += p * v0.y; acc0.z += p * v0.z; acc0.w += p * v0.w;
            acc1.x += p * v1.x; acc1.y += p * v1.y; acc1.z += p * v1.z; acc1.w += p * v1.w;
        }
    }
    acc0.x *= inv; acc0.y *= inv; acc0.z *= inv; acc0.w *= inv;
    acc1.x *= inv; acc1.y *= inv; acc1.z *= inv; acc1.w *= inv;
    float4* ctx4 = (float4*)(context + (size_t)b * E);
    ctx4[tid] = acc0;
    ctx4[256 + tid] = acc1;
}

// ---------------------------------------------------------------------------
extern "C" void kernel_launch(void* const* d_in, const int* in_sizes, int n_in,
                              void* d_out, int out_size, void* d_ws, size_t ws_size,
                              hipStream_t stream) {
    const float* query = (const float*)d_in[0];   // [B,1,H]
    const float* value = (const float*)d_in[1];   // [B,S,E]
    const int*   mask  = (const int*)d_in[2];     // [B,1,S]
    const float* W_enc = (const float*)d_in[3];   // [H,E]
    const float* W_q   = (const float*)d_in[4];   // [H,H]
    const float* W_bil = (const float*)d_in[5];   // [H,H]

    float* out = (float*)d_out;
    float* context = out;          // [B,1,E]
    float* alphas  = out + B * E;  // [B,1,S]

    float* ws = (float*)d_ws;
    float* qp    = ws;                           // B*H
    float* qw    = qp + B * H;                   // B*H
    float* u     = qw + B * H;                   // B*E
    float* sc_ws = u + B * E;                    // B*S
    float* qwp   = sc_ws + B * S;                // 64*B*H (4 MB)
    float* up    = qwp + (size_t)64 * B * H;     // 32*B*E (4 MB)

    // Single-node chain: cooperative kernel with grid syncs between stages
    void* args[] = {(void*)&query, (void*)&W_q, (void*)&W_bil, (void*)&W_enc,
                    (void*)&qp, (void*)&qwp, (void*)&qw, (void*)&up, (void*)&u};
    hipLaunchCooperativeKernel((const void*)k_chain_coop, dim3(256), dim3(256),
                               args, 0, stream);

    // Scores (the 268 MB HBM stream)
    k_scores<<<dim3(S / 16, B), 256, 0, stream>>>(u, value, mask, sc_ws);

    // Softmax + alphas + context
    k_smctx<<<dim3(B), 256, 0, stream>>>(sc_ws, value, alphas, context);
}